// Round 5
// baseline (737.782 us; speedup 1.0000x reference)
//
#include <hip/hip_runtime.h>
#include <math.h>

#define GN  4
#define MCN 100
#define BN  512
#define INN 456
#define HN  400
#define ON  10
#define HP  416   // padded K extent (zeros in [400,416))

// softplus(s)^2, numerically stable
__device__ __forceinline__ float sp2f(float s) {
    float l = log1pf(__expf(-fabsf(s)));
    float r = fmaxf(s, 0.0f) + l;
    return r * r;
}

typedef float f4v __attribute__((ext_vector_type(4)));
typedef float f2v __attribute__((ext_vector_type(2)));

// nontemporal stream loads: zeta1/zeta3 are read-once; keep them from
// thrashing the fill-dirtied L2/L3 (R2 counters: 99MB of inherited
// writebacks during k_layer2).
__device__ __forceinline__ f4v nt4(const float* p) {
    return __builtin_nontemporal_load((const f4v*)p);
}
__device__ __forceinline__ float nt1(const float* p) {
    return __builtin_nontemporal_load(p);
}

// DPP sum across 16-lane groups (lane bits 0-3). All VALU (v_add_f32_dpp).
#define DPP_ADD(v, CTRL) \
    ((v) + __int_as_float(__builtin_amdgcn_update_dpp( \
        0, __float_as_int(v), (CTRL), 0xF, 0xF, true)))

__device__ __forceinline__ float reduce16(float v) {
    v = DPP_ADD(v, 0xB1);    // quad_perm [1,0,3,2]  == xor 1
    v = DPP_ADD(v, 0x4E);    // quad_perm [2,3,0,1]  == xor 2
    v = DPP_ADD(v, 0x124);   // row_ror:4
    v = DPP_ADD(v, 0x128);   // row_ror:8
    return v;
}

// ---------------- kernel 0a: x -> xT, x^2 -> xxT (tiled transpose) ----------------
__global__ __launch_bounds__(256) void k_transpose(
    const float* __restrict__ x, float* __restrict__ xT, float* __restrict__ xxT) {
    __shared__ float tile[64][65];
    int it = blockIdx.x;           // i tile (8 tiles, tail: 456 = 7*64 + 8)
    int bt = blockIdx.y;           // b tile (8 tiles of 64)
    int tx = threadIdx.x & 63;
    int ty = threadIdx.x >> 6;     // 0..3
    int i_in = it * 64 + tx;
    #pragma unroll
    for (int r = 0; r < 16; ++r) {
        int row = r * 4 + ty;
        int b = bt * 64 + row;
        tile[row][tx] = (i_in < INN) ? x[b * INN + i_in] : 0.0f;
    }
    __syncthreads();
    #pragma unroll
    for (int r = 0; r < 16; ++r) {
        int row = r * 4 + ty;
        int i = it * 64 + row;
        if (i < INN) {
            float v = tile[tx][row];           // stride 65 -> conflict-free
            xT[i * BN + bt * 64 + tx]  = v;
            xxT[i * BN + bt * 64 + tx] = v * v;
        }
    }
}

// ---------------- kernel 0b: sp1 = softplus(sigma1)^2, sp3 = softplus(sigma3)^2 ----
__global__ __launch_bounds__(256) void k_sp(
    const float* __restrict__ sigma1, const float* __restrict__ sigma3,
    float* __restrict__ sp1, float* __restrict__ sp3) {
    int idx = blockIdx.x * 256 + threadIdx.x;
    const int n1 = GN * INN * HN / 4;   // 182400 quads
    const int n3 = GN * HN * ON / 4;    // 4000 quads
    if (idx < n1) {
        float4 s = ((const float4*)sigma1)[idx];
        float4 o;
        o.x = sp2f(s.x); o.y = sp2f(s.y); o.z = sp2f(s.z); o.w = sp2f(s.w);
        ((float4*)sp1)[idx] = o;
    } else if (idx < n1 + n3) {
        int k = idx - n1;
        float4 s = ((const float4*)sigma3)[k];
        float4 o;
        o.x = sp2f(s.x); o.y = sp2f(s.y); o.z = sp2f(s.z); o.w = sp2f(s.w);
        ((float4*)sp3)[k] = o;
    }
}

// ---------------- kernel 1: A = x@mu1, S = sqrt((x*x)@sp1) ---------------- (unchanged)
__global__ __launch_bounds__(256) void k_layer1(
    const float* __restrict__ xT, const float* __restrict__ xxT,
    const float* __restrict__ mu1, const float* __restrict__ sp1,
    float* __restrict__ A, float* __restrict__ S) {
    int bt = blockIdx.x;            // 0..31
    int ht = blockIdx.y;            // 0..6
    int g  = blockIdx.z;            // 0..3
    int lane = threadIdx.x & 63;
    int wv   = threadIdx.x >> 6;    // 0..3
    int h = ht * 64 + lane;
    bool hv = h < HN;
    int hc = hv ? h : (HN - 1);     // clamp so masked lanes stay in-bounds
    int b0 = __builtin_amdgcn_readfirstlane(bt * 16 + wv * 4);
    const float* mp = mu1 + (size_t)g * INN * HN + hc;
    const float* pp = sp1 + (size_t)g * INN * HN + hc;
    float accA[4] = {0.f, 0.f, 0.f, 0.f};
    float accD[4] = {0.f, 0.f, 0.f, 0.f};
    #pragma unroll 4
    for (int k = 0; k < INN; ++k) {
        float a = mp[(size_t)k * HN];
        float p = pp[(size_t)k * HN];
        float4 xv  = *(const float4*)(xT  + k * BN + b0);   // wave-uniform 16B
        float4 xxv = *(const float4*)(xxT + k * BN + b0);
        accA[0] = fmaf(a, xv.x,  accA[0]);
        accA[1] = fmaf(a, xv.y,  accA[1]);
        accA[2] = fmaf(a, xv.z,  accA[2]);
        accA[3] = fmaf(a, xv.w,  accA[3]);
        accD[0] = fmaf(p, xxv.x, accD[0]);
        accD[1] = fmaf(p, xxv.y, accD[1]);
        accD[2] = fmaf(p, xxv.z, accD[2]);
        accD[3] = fmaf(p, xxv.w, accD[3]);
    }
    if (hv) {
        #pragma unroll
        for (int j = 0; j < 4; ++j) {
            size_t o = ((size_t)g * BN + (b0 + j)) * HN + h;
            A[o] = accA[j];
            S[o] = sqrtf(accD[j]);
        }
    }
}

// ---------------- kernel 2: layer 2 + softmax + MC mean ----------------
// R5: widen the zeta1 stream again (R4's vectorization was the only change
// since R0 that moved the needle: ~190 -> ~160us).
//  - lane map t = [rgg(2b) | og(1b) | kc(5b)]: 32-lane kc group reads 512B
//    contiguous per global_load_dwordx4 (2x R4), half the VMEM instrs/streams.
//  - j in [0,3): k = 4*kc + 128*j covers [0,384); scalar 32-wide tail covers
//    k in [384,416) with A/S/W zero-padded in [400,416) (contributes exactly 0;
//    zeta load index clamped to 399 for bounds safety).
//  - chunks: 6 x 16 rows + 1 x 4 rows = exactly 100 MC rows (no clamp waste).
//  - reduce: 4xDPP within 16 lanes; kc bit-4 resolved by writing TWO epi
//    halves (kc==0 and kc==16 lanes), summed in the epilogue. No 5th shuffle.
//  - planar a_s/s_s (interleaved float4 read was a 4-8-way bank conflict).
//  - zeta1/zeta3 nontemporal; z3 prefetched at chunk start.
//  - XCD-bijective swizzle: consecutive b (adjacent 1600B zeta rows) share an
//    XCD's L2 (2048 blocks % 8 == 0 -> bijective).
template<int NI>
__device__ __forceinline__ void mc_chunk(
    int g, int b, int mb, int kc, int og, int rgg, int t,
    const float* __restrict__ zeta1, const float* __restrict__ zeta3,
    const float* a_s, const float* s_s, const float* wp,
    float* epi, float* psum) {
    const int NR = NI * 4;     // rows in this chunk

    // epilogue zeta3 prefetch (rows mb..mb+NR-1, all < MCN by construction)
    float z3r[ON];
    if (t < NR) {
        const float* z3p = zeta3 + ((size_t)(g * MCN + mb + t) * BN + b) * ON;
        #pragma unroll
        for (int o = 0; o < ON; ++o) z3r[o] = nt1(z3p + o);
    }

    float acc[NI][ON];
    #pragma unroll
    for (int i = 0; i < NI; ++i)
        #pragma unroll
        for (int o = 0; o < ON; ++o) acc[i][o] = 0.0f;

    const float* zp[NI];
    #pragma unroll
    for (int i = 0; i < NI; ++i) {
        int m = mb + rgg + 4 * i;            // always < MCN
        zp[i] = zeta1 + ((size_t)(g * MCN + m) * BN + b) * HN + 4 * kc;
    }

    // depth-1 float4 zeta pipeline (each load covers 4 k, 512B/32-lane group)
    f4v zc[NI];
    #pragma unroll
    for (int i = 0; i < NI; ++i) zc[i] = nt4(zp[i]);

    #pragma unroll 1
    for (int j = 0; j < 3; ++j) {
        f4v zn[NI];
        if (j < 2) {
            #pragma unroll
            for (int i = 0; i < NI; ++i) zn[i] = nt4(zp[i] + 128 * (j + 1));
        } else {
            #pragma unroll
            for (int i = 0; i < NI; ++i) zn[i] = zc[i];   // dummy
        }
        int k0 = 4 * kc + 128 * j;
        f4v Av = *(const f4v*)(a_s + k0);
        f4v Sv = *(const f4v*)(s_s + k0);
        f4v W[ON];
        #pragma unroll
        for (int o = 0; o < ON; ++o) W[o] = *(const f4v*)(wp + o * HP + k0);
        #pragma unroll
        for (int i = 0; i < NI; ++i) {
            float h0 = fmaxf(0.0f, fmaf(Sv[0], zc[i][0], Av[0]));
            float h1 = fmaxf(0.0f, fmaf(Sv[1], zc[i][1], Av[1]));
            float h2 = fmaxf(0.0f, fmaf(Sv[2], zc[i][2], Av[2]));
            float h3 = fmaxf(0.0f, fmaf(Sv[3], zc[i][3], Av[3]));
            float c0 = og ? h0 * h0 : h0;    // branchless og select
            float c1 = og ? h1 * h1 : h1;
            float c2 = og ? h2 * h2 : h2;
            float c3 = og ? h3 * h3 : h3;
            #pragma unroll
            for (int o = 0; o < ON; ++o) {
                acc[i][o] = fmaf(c0, W[o][0], acc[i][o]);
                acc[i][o] = fmaf(c1, W[o][1], acc[i][o]);
                acc[i][o] = fmaf(c2, W[o][2], acc[i][o]);
                acc[i][o] = fmaf(c3, W[o][3], acc[i][o]);
            }
        }
        #pragma unroll
        for (int i = 0; i < NI; ++i) zc[i] = zn[i];
    }

    // tail: one k per lane, k = 384 + kc (kc >= 16 hits the zero pad -> +0)
    {
        int k_as = 384 + kc;                      // [384,416), pad-safe
        int k_z  = (kc < 16) ? (384 + kc) : 399;  // clamp load for bounds
        int dz   = k_z - 4 * kc;                  // zp already includes +4*kc
        float Aa = a_s[k_as];
        float Ss = s_s[k_as];
        float wt[ON];
        #pragma unroll
        for (int o = 0; o < ON; ++o) wt[o] = wp[o * HP + k_as];
        #pragma unroll
        for (int i = 0; i < NI; ++i) {
            float z  = nt1(zp[i] + dz);
            float hv = fmaxf(0.0f, fmaf(Ss, z, Aa));
            float c  = og ? hv * hv : hv;
            #pragma unroll
            for (int o = 0; o < ON; ++o) acc[i][o] = fmaf(c, wt[o], acc[i][o]);
        }
    }

    // reduce across 16 kc lanes (pure VALU DPP)
    #pragma unroll
    for (int i = 0; i < NI; ++i)
        #pragma unroll
        for (int o = 0; o < ON; ++o) acc[i][o] = reduce16(acc[i][o]);

    // kc==0 and kc==16 lanes hold the two 16-lane partials -> two epi halves
    if ((kc & 15) == 0) {
        int half = kc >> 4;
        #pragma unroll
        for (int i = 0; i < NI; ++i) {
            int rl = rgg + 4 * i;
            #pragma unroll
            for (int o = 0; o < ON; ++o)
                epi[(rl * ON + o) * 4 + og * 2 + half] = acc[i][o];
        }
    }
    __syncthreads();

    // epilogue: one thread per MC row of this chunk (z3 already in regs)
    if (t < NR) {
        float ov[ON];
        float mx = 0.0f;
        #pragma unroll
        for (int o = 0; o < ON; ++o) {
            const float* e = epi + (t * ON + o) * 4;
            float gg = e[0] + e[1];
            float gd = e[2] + e[3];
            float v = fmaf(sqrtf(gd), z3r[o], gg);
            v = fmaxf(v, 0.0f);
            ov[o] = v;
            mx = fmaxf(mx, v);
        }
        float se = 0.0f;
        #pragma unroll
        for (int o = 0; o < ON; ++o) { float e = __expf(ov[o] - mx); ov[o] = e; se += e; }
        float r = 1.0f / se;
        #pragma unroll
        for (int o = 0; o < ON; ++o) psum[o] = fmaf(ov[o], r, psum[o]);
    }
    __syncthreads();   // protect epi from next chunk's writers
}

__global__ __launch_bounds__(256, 3) void k_layer2(
    const float* __restrict__ A, const float* __restrict__ S,
    const float* __restrict__ mu3, const float* __restrict__ sp3,
    const float* __restrict__ zeta1, const float* __restrict__ zeta3,
    float* __restrict__ out) {
    // XCD-bijective swizzle: 2048 blocks, 8 XCDs -> consecutive b per XCD
    int lin = blockIdx.x + BN * blockIdx.y;          // 0..2047
    int nid = (lin & 7) * (BN * GN / 8) + (lin >> 3);
    int b = nid & (BN - 1);
    int g = nid >> 9;

    // Transposed, K-padded weight planes: wT[o][k], vT[o][k], k in [0,416).
    // 32-lane b128 reads span 512B contiguous -> conflict-free.
    // LDS: 16640*2 + 1664*2 + 2560 + 640 = 39808 B -> 4 blocks/CU by LDS.
    __shared__ __align__(16) float wT_s[ON * HP];     // 16640 B
    __shared__ __align__(16) float vT_s[ON * HP];     // 16640 B
    __shared__ __align__(16) float a_s[HP];           //  1664 B
    __shared__ __align__(16) float s_s[HP];           //  1664 B
    __shared__ __align__(16) float epi[16 * ON * 4];  //  2560 B [row][o][og][half]
    __shared__ __align__(16) float psh[16 * ON];      //   640 B

    int t = threadIdx.x;

    {   // stage weights transposed (h-major global -> o-major LDS)
        const float* wsrc = mu3 + (size_t)g * HN * ON;
        const float* vsrc = sp3 + (size_t)g * HN * ON;
        for (int i = t; i < HN * ON; i += 256) {
            int h = i / ON, o = i - h * ON;
            wT_s[o * HP + h] = wsrc[i];
            vT_s[o * HP + h] = vsrc[i];
        }
        // zero the K pad [400,416) of both planes (160 slots each)
        for (int i = t; i < (HP - HN) * ON; i += 256) {
            int o = i / (HP - HN), h = HN + i % (HP - HN);
            wT_s[o * HP + h] = 0.0f;
            vT_s[o * HP + h] = 0.0f;
        }
    }
    for (int i = t; i < HP; i += 256) {
        if (i < HN) {
            size_t src = ((size_t)g * BN + b) * HN + i;
            a_s[i] = A[src];
            s_s[i] = S[src];
        } else {
            a_s[i] = 0.0f;    // pad: hv = relu(0*z+0) = 0 -> contributes 0
            s_s[i] = 0.0f;
        }
    }
    __syncthreads();

    int kc  = t & 31;
    int og  = (t >> 5) & 1;
    int rgg = t >> 6;            // 0..3

    const float* wp = og ? vT_s : wT_s;

    float psum[ON];
    #pragma unroll
    for (int o = 0; o < ON; ++o) psum[o] = 0.0f;

    #pragma unroll 1
    for (int c = 0; c < 6; ++c)
        mc_chunk<4>(g, b, c * 16, kc, og, rgg, t, zeta1, zeta3, a_s, s_s, wp, epi, psum);
    mc_chunk<1>(g, b, 96, kc, og, rgg, t, zeta1, zeta3, a_s, s_s, wp, epi, psum);

    // psums live in threads t<16 (rows t, 16+t, ..., 80+t; t<4 also 96+t)
    if (t < 16) {
        #pragma unroll
        for (int o = 0; o < ON; ++o) psh[t * ON + o] = psum[o];
    }
    __syncthreads();
    if (t < ON) {
        float s = 0.0f;
        #pragma unroll
        for (int r = 0; r < 16; ++r) s += psh[r * ON + t];
        out[b * (GN * ON) + g * ON + t] = s * (1.0f / MCN);   // direct store
    }
}

extern "C" void kernel_launch(void* const* d_in, const int* in_sizes, int n_in,
                              void* d_out, int out_size, void* d_ws, size_t ws_size,
                              hipStream_t stream) {
    const float* x      = (const float*)d_in[0];
    const float* mu1    = (const float*)d_in[1];
    const float* sigma1 = (const float*)d_in[2];
    const float* mu3    = (const float*)d_in[3];
    const float* sigma3 = (const float*)d_in[4];
    const float* zeta1  = (const float*)d_in[5];
    const float* zeta3  = (const float*)d_in[6];
    // d_in[7] = num (always 3 -> G = 4, baked into GN)

    float* ws  = (float*)d_ws;
    float* xT  = ws;                       // 456*512
    float* xxT = xT  + INN * BN;           // 456*512
    float* sp1 = xxT + INN * BN;           // 4*456*400
    float* sp3 = sp1 + GN * INN * HN;      // 4*400*10
    float* A   = sp3 + GN * HN * ON;       // 4*512*400
    float* S   = A   + GN * BN * HN;       // 4*512*400
    float* out = (float*)d_out;            // 512*40

    const int nsp = GN * INN * HN / 4 + GN * HN * ON / 4;   // 186400
    k_transpose<<<dim3(8, 8), 256, 0, stream>>>(x, xT, xxT);
    k_sp<<<dim3((nsp + 255) / 256), 256, 0, stream>>>(sigma1, sigma3, sp1, sp3);
    k_layer1<<<dim3(32, 7, GN), 256, 0, stream>>>(xT, xxT, mu1, sp1, A, S);
    k_layer2<<<dim3(BN, GN), 256, 0, stream>>>(A, S, mu3, sp3, zeta1, zeta3, out);
}

// Round 6
// 609.625 us; speedup vs baseline: 1.2102x; 1.2102x over previous
//
#include <hip/hip_runtime.h>
#include <math.h>

#define GN  4
#define MCN 100
#define BN  512
#define INN 456
#define HN  400
#define ON  10

// softplus(s)^2, numerically stable
__device__ __forceinline__ float sp2f(float s) {
    float l = log1pf(__expf(-fabsf(s)));
    float r = fmaxf(s, 0.0f) + l;
    return r * r;
}

typedef float f4v __attribute__((ext_vector_type(4)));

// nontemporal stream loads: zeta1/zeta3 are read-once (347MB); don't allocate
// them in L2/L3, so the harness-fill's dirty lines aren't evicted (R2 showed
// ~99MB of inherited writebacks taxing this kernel's HBM stream).
__device__ __forceinline__ f4v nt4(const float* p) {
    return __builtin_nontemporal_load((const f4v*)p);
}
__device__ __forceinline__ float nt1(const float* p) {
    return __builtin_nontemporal_load(p);
}

// DPP sum across the 16-lane group (lane bits 0-3 = kc). xor1, xor2 (quad
// sums), then ror4 + ror8 complete the 16-sum in every lane. All VALU
// (v_add_f32_dpp) -- keeps the reduction OFF the LDS pipe.
#define DPP_ADD(v, CTRL) \
    ((v) + __int_as_float(__builtin_amdgcn_update_dpp( \
        0, __float_as_int(v), (CTRL), 0xF, 0xF, true)))

__device__ __forceinline__ float reduce16(float v) {
    v = DPP_ADD(v, 0xB1);    // quad_perm [1,0,3,2]  == xor 1
    v = DPP_ADD(v, 0x4E);    // quad_perm [2,3,0,1]  == xor 2
    v = DPP_ADD(v, 0x124);   // row_ror:4
    v = DPP_ADD(v, 0x128);   // row_ror:8
    return v;
}

// ---------------- kernel 0a: x -> xT, x^2 -> xxT (tiled transpose) ----------------
__global__ __launch_bounds__(256) void k_transpose(
    const float* __restrict__ x, float* __restrict__ xT, float* __restrict__ xxT) {
    __shared__ float tile[64][65];
    int it = blockIdx.x;           // i tile (8 tiles, tail: 456 = 7*64 + 8)
    int bt = blockIdx.y;           // b tile (8 tiles of 64)
    int tx = threadIdx.x & 63;
    int ty = threadIdx.x >> 6;     // 0..3
    int i_in = it * 64 + tx;
    #pragma unroll
    for (int r = 0; r < 16; ++r) {
        int row = r * 4 + ty;
        int b = bt * 64 + row;
        tile[row][tx] = (i_in < INN) ? x[b * INN + i_in] : 0.0f;
    }
    __syncthreads();
    #pragma unroll
    for (int r = 0; r < 16; ++r) {
        int row = r * 4 + ty;
        int i = it * 64 + row;
        if (i < INN) {
            float v = tile[tx][row];           // stride 65 -> conflict-free
            xT[i * BN + bt * 64 + tx]  = v;
            xxT[i * BN + bt * 64 + tx] = v * v;
        }
    }
}

// ---------------- kernel 0b: sp1 = softplus(sigma1)^2, sp3 = softplus(sigma3)^2 ----
__global__ __launch_bounds__(256) void k_sp(
    const float* __restrict__ sigma1, const float* __restrict__ sigma3,
    float* __restrict__ sp1, float* __restrict__ sp3) {
    int idx = blockIdx.x * 256 + threadIdx.x;
    const int n1 = GN * INN * HN / 4;   // 182400 quads
    const int n3 = GN * HN * ON / 4;    // 4000 quads
    if (idx < n1) {
        float4 s = ((const float4*)sigma1)[idx];
        float4 o;
        o.x = sp2f(s.x); o.y = sp2f(s.y); o.z = sp2f(s.z); o.w = sp2f(s.w);
        ((float4*)sp1)[idx] = o;
    } else if (idx < n1 + n3) {
        int k = idx - n1;
        float4 s = ((const float4*)sigma3)[k];
        float4 o;
        o.x = sp2f(s.x); o.y = sp2f(s.y); o.z = sp2f(s.z); o.w = sp2f(s.w);
        ((float4*)sp3)[k] = o;
    }
}

// ---------------- kernel 1: A = x@mu1, S = sqrt((x*x)@sp1) ---------------- (unchanged)
__global__ __launch_bounds__(256) void k_layer1(
    const float* __restrict__ xT, const float* __restrict__ xxT,
    const float* __restrict__ mu1, const float* __restrict__ sp1,
    float* __restrict__ A, float* __restrict__ S) {
    int bt = blockIdx.x;            // 0..31
    int ht = blockIdx.y;            // 0..6
    int g  = blockIdx.z;            // 0..3
    int lane = threadIdx.x & 63;
    int wv   = threadIdx.x >> 6;    // 0..3
    int h = ht * 64 + lane;
    bool hv = h < HN;
    int hc = hv ? h : (HN - 1);     // clamp so masked lanes stay in-bounds
    int b0 = __builtin_amdgcn_readfirstlane(bt * 16 + wv * 4);
    const float* mp = mu1 + (size_t)g * INN * HN + hc;
    const float* pp = sp1 + (size_t)g * INN * HN + hc;
    float accA[4] = {0.f, 0.f, 0.f, 0.f};
    float accD[4] = {0.f, 0.f, 0.f, 0.f};
    #pragma unroll 4
    for (int k = 0; k < INN; ++k) {
        float a = mp[(size_t)k * HN];
        float p = pp[(size_t)k * HN];
        float4 xv  = *(const float4*)(xT  + k * BN + b0);   // wave-uniform 16B
        float4 xxv = *(const float4*)(xxT + k * BN + b0);
        accA[0] = fmaf(a, xv.x,  accA[0]);
        accA[1] = fmaf(a, xv.y,  accA[1]);
        accA[2] = fmaf(a, xv.z,  accA[2]);
        accA[3] = fmaf(a, xv.w,  accA[3]);
        accD[0] = fmaf(p, xxv.x, accD[0]);
        accD[1] = fmaf(p, xxv.y, accD[1]);
        accD[2] = fmaf(p, xxv.z, accD[2]);
        accD[3] = fmaf(p, xxv.w, accD[3]);
    }
    if (hv) {
        #pragma unroll
        for (int j = 0; j < 4; ++j) {
            size_t o = ((size_t)g * BN + (b0 + j)) * HN + h;
            A[o] = accA[j];
            S[o] = sqrtf(accD[j]);
        }
    }
}

// ---------------- kernel 2: layer 2 + softmax + MC mean ----------------
// R6 = revert to R4 (best measured: ~160us) + two surgical, independent fixes.
// R5's regression decomposed: (a) HP=416 stride made every W b128 read an
// 8-way bank conflict (416 % 32 == 0; R4's 400 % 32 == 16 alternates banks
// per o); (b) z3r prefetch + widened f4 pipeline state spilled (WRITE_SIZE
// +200MB, VGPR squeezed to 84). Both reverted.
// Kept from R5 (orthogonal, verified-safe):
//  - planar a_s/s_s: R4's interleaved as_s float4 read had banks 8kc%32 ->
//    genuine 4-way conflict; planar f4 reads at 4kc%32 are 2-way (free).
//  - nontemporal zeta1/zeta3 loads (read-once streams; avoid L2/L3 pollution
//    + dirty-fill-line eviction writebacks).
// Lane map: t = [rgg(3b) | og(1b) | kc(4b)]; og=0 -> h*w, og=1 -> h^2*v.
// k = 4*kc + 64*j, j<6, + 16-wide scalar tail (k=384+kc < 400).
template<int NI>
__device__ __forceinline__ void mc_chunk(
    int g, int b, int mb, int kc, int og, int rgg, int t,
    const float* __restrict__ zeta1, const float* __restrict__ zeta3,
    const float* a_s, const float* s_s, const float* wp,
    float* epi, float* psum) {
    const int NR = NI * 8;

    float acc[NI][ON];
    #pragma unroll
    for (int i = 0; i < NI; ++i)
        #pragma unroll
        for (int o = 0; o < ON; ++o) acc[i][o] = 0.0f;

    const float* zp[NI];
    #pragma unroll
    for (int i = 0; i < NI; ++i) {
        int m = mb + rgg + 8 * i;
        int mcl = m < MCN ? m : (MCN - 1);   // clamp loads; result discarded
        zp[i] = zeta1 + ((size_t)(g * MCN + mcl) * BN + b) * HN + 4 * kc;
    }

    // depth-1 float4 zeta pipeline (each load covers 4 k; 256B/16-lane group)
    f4v zc[NI];
    #pragma unroll
    for (int i = 0; i < NI; ++i) zc[i] = nt4(zp[i]);

    #pragma unroll 1
    for (int j = 0; j < 6; ++j) {
        f4v zn[NI];
        if (j < 5) {
            #pragma unroll
            for (int i = 0; i < NI; ++i) zn[i] = nt4(zp[i] + 64 * (j + 1));
        } else {
            #pragma unroll
            for (int i = 0; i < NI; ++i) zn[i] = zc[i];   // dummy
        }
        int k0 = 4 * kc + 64 * j;
        f4v Av = *(const f4v*)(a_s + k0);    // banks 4kc%32: 2-way = free
        f4v Sv = *(const f4v*)(s_s + k0);
        // weights: 10 rows x 4 consecutive k (b128 each), stride 400 (%32=16)
        f4v W[ON];
        #pragma unroll
        for (int o = 0; o < ON; ++o) W[o] = *(const f4v*)(wp + o * HN + k0);
        #pragma unroll
        for (int i = 0; i < NI; ++i) {
            float h0 = fmaxf(0.0f, fmaf(Sv[0], zc[i][0], Av[0]));
            float h1 = fmaxf(0.0f, fmaf(Sv[1], zc[i][1], Av[1]));
            float h2 = fmaxf(0.0f, fmaf(Sv[2], zc[i][2], Av[2]));
            float h3 = fmaxf(0.0f, fmaf(Sv[3], zc[i][3], Av[3]));
            float c0 = og ? h0 * h0 : h0;    // branchless og select
            float c1 = og ? h1 * h1 : h1;
            float c2 = og ? h2 * h2 : h2;
            float c3 = og ? h3 * h3 : h3;
            #pragma unroll
            for (int o = 0; o < ON; ++o) {
                acc[i][o] = fmaf(c0, W[o][0], acc[i][o]);
                acc[i][o] = fmaf(c1, W[o][1], acc[i][o]);
                acc[i][o] = fmaf(c2, W[o][2], acc[i][o]);
                acc[i][o] = fmaf(c3, W[o][3], acc[i][o]);
            }
        }
        #pragma unroll
        for (int i = 0; i < NI; ++i) zc[i] = zn[i];
    }

    // tail: k = 384 + kc (16 k across the kc lanes, all < 400)
    {
        int k = 384 + kc;
        int toff = 384 - 3 * kc;             // zp is row + 4*kc; want row + 384 + kc
        float Aa = a_s[k];
        float Ss = s_s[k];
        float wt[ON];
        #pragma unroll
        for (int o = 0; o < ON; ++o) wt[o] = wp[o * HN + k];
        #pragma unroll
        for (int i = 0; i < NI; ++i) {
            float z = nt1(zp[i] + toff);
            float hv = fmaxf(0.0f, fmaf(Ss, z, Aa));
            float c = og ? hv * hv : hv;
            #pragma unroll
            for (int o = 0; o < ON; ++o) acc[i][o] = fmaf(c, wt[o], acc[i][o]);
        }
    }

    // reduce across the 16 kc lanes (DPP stays on the VALU pipe)
    #pragma unroll
    for (int i = 0; i < NI; ++i)
        #pragma unroll
        for (int o = 0; o < ON; ++o) acc[i][o] = reduce16(acc[i][o]);

    if (kc == 0) {
        #pragma unroll
        for (int i = 0; i < NI; ++i) {
            int rl = rgg + 8 * i;
            #pragma unroll
            for (int o = 0; o < ON; ++o)
                epi[(rl * ON + o) * 2 + og] = acc[i][o];   // interleave {g,d}
        }
    }
    __syncthreads();

    // epilogue: one thread per MC row of this chunk
    if (t < NR) {
        int m = mb + t;
        if (m < MCN) {
            const float* z3p = zeta3 + ((size_t)(g * MCN + m) * BN + b) * ON;
            float ov[ON];
            float mx = 0.0f;
            #pragma unroll
            for (int o = 0; o < ON; ++o) {
                float2 gd = *(const float2*)(epi + (t * ON + o) * 2);
                float v = fmaf(sqrtf(gd.y), nt1(z3p + o), gd.x);
                v = fmaxf(v, 0.0f);
                ov[o] = v;
                mx = fmaxf(mx, v);
            }
            float se = 0.0f;
            #pragma unroll
            for (int o = 0; o < ON; ++o) { float e = __expf(ov[o] - mx); ov[o] = e; se += e; }
            float r = 1.0f / se;
            #pragma unroll
            for (int o = 0; o < ON; ++o) psum[o] = fmaf(ov[o], r, psum[o]);
        }
    }
    __syncthreads();   // protect epi from next chunk's writers
}

__global__ __launch_bounds__(256, 3) void k_layer2(
    const float* __restrict__ A, const float* __restrict__ S,
    const float* __restrict__ mu3, const float* __restrict__ sp3,
    const float* __restrict__ zeta1, const float* __restrict__ zeta3,
    float* __restrict__ out) {
    int b = blockIdx.x;   // 0..511
    int g = blockIdx.y;   // 0..3

    // Transposed weight planes: wT[o][h] = mu3[g][h][o], vT[o][h] = sp3[g][h][o].
    // Stride 400 floats (%32 = 16): per-o bank sets alternate -> ~4-way worst
    // case on W b128 reads (R4-measured acceptable).
    // LDS: 16000*2 + 1600*2 + 2560 + 1280 = 39040 B.
    __shared__ __align__(16) float wT_s[ON * HN];     // 16000 B
    __shared__ __align__(16) float vT_s[ON * HN];     // 16000 B
    __shared__ __align__(16) float a_s[HN];           //  1600 B
    __shared__ __align__(16) float s_s[HN];           //  1600 B
    __shared__ __align__(16) float epi[32 * ON * 2];  //  2560 B, [row][o][{g,d}]
    __shared__ __align__(16) float psh[32 * ON];      //  1280 B

    int t = threadIdx.x;

    {   // stage weights transposed (h-major global -> o-major LDS)
        const float* wsrc = mu3 + (size_t)g * HN * ON;
        const float* vsrc = sp3 + (size_t)g * HN * ON;
        for (int i = t; i < HN * ON; i += 256) {
            int h = i / ON, o = i - h * ON;
            wT_s[o * HN + h] = wsrc[i];
            vT_s[o * HN + h] = vsrc[i];
        }
    }
    for (int i = t; i < HN; i += 256) {
        size_t src = ((size_t)g * BN + b) * HN + i;
        a_s[i] = A[src];
        s_s[i] = S[src];
    }
    __syncthreads();

    int kc  = t & 15;
    int og  = (t >> 4) & 1;
    int rgg = t >> 5;            // 0..7

    const float* wp = og ? vT_s : wT_s;

    float psum[ON];
    #pragma unroll
    for (int o = 0; o < ON; ++o) psum[o] = 0.0f;

    #pragma unroll 1
    for (int c = 0; c < 3; ++c)
        mc_chunk<4>(g, b, c * 32, kc, og, rgg, t, zeta1, zeta3, a_s, s_s, wp, epi, psum);
    mc_chunk<1>(g, b, 96, kc, og, rgg, t, zeta1, zeta3, a_s, s_s, wp, epi, psum);

    if (t < 32) {
        #pragma unroll
        for (int o = 0; o < ON; ++o) psh[t * ON + o] = psum[o];
    }
    __syncthreads();
    if (t < ON) {
        float s = 0.0f;
        #pragma unroll
        for (int r = 0; r < 32; ++r) s += psh[r * ON + t];
        out[b * (GN * ON) + g * ON + t] = s * (1.0f / MCN);   // direct store
    }
}

extern "C" void kernel_launch(void* const* d_in, const int* in_sizes, int n_in,
                              void* d_out, int out_size, void* d_ws, size_t ws_size,
                              hipStream_t stream) {
    const float* x      = (const float*)d_in[0];
    const float* mu1    = (const float*)d_in[1];
    const float* sigma1 = (const float*)d_in[2];
    const float* mu3    = (const float*)d_in[3];
    const float* sigma3 = (const float*)d_in[4];
    const float* zeta1  = (const float*)d_in[5];
    const float* zeta3  = (const float*)d_in[6];
    // d_in[7] = num (always 3 -> G = 4, baked into GN)

    float* ws  = (float*)d_ws;
    float* xT  = ws;                       // 456*512
    float* xxT = xT  + INN * BN;           // 456*512
    float* sp1 = xxT + INN * BN;           // 4*456*400
    float* sp3 = sp1 + GN * INN * HN;      // 4*400*10
    float* A   = sp3 + GN * HN * ON;       // 4*512*400
    float* S   = A   + GN * BN * HN;       // 4*512*400
    float* out = (float*)d_out;            // 512*40

    const int nsp = GN * INN * HN / 4 + GN * HN * ON / 4;   // 186400
    k_transpose<<<dim3(8, 8), 256, 0, stream>>>(x, xT, xxT);
    k_sp<<<dim3((nsp + 255) / 256), 256, 0, stream>>>(sigma1, sigma3, sp1, sp3);
    k_layer1<<<dim3(32, 7, GN), 256, 0, stream>>>(xT, xxT, mu1, sp1, A, S);
    k_layer2<<<dim3(BN, GN), 256, 0, stream>>>(A, S, mu3, sp3, zeta1, zeta3, out);
}